// Round 20
// baseline (344.280 us; speedup 1.0000x reference)
//
#include <hip/hip_runtime.h>
#include <hip/hip_fp16.h>

#define BB 32
#define SS 8192
#define CC 128
#define MM 16
#define NUMK 8
#define NL 4

#define TWO_PI 6.2831853071795864769f

typedef _Float16 f16x8 __attribute__((ext_vector_type(8)));
typedef float f32x4 __attribute__((ext_vector_type(4)));

#define MFMA16(a, b, c) __builtin_amdgcn_mfma_f32_16x16x32_f16((a), (b), (c), 0, 0, 0)

// tanh-form GELU (max dev from exact erf-GELU ~3e-4, threshold 1.9e-2)
__device__ __forceinline__ float gelu_f(float v) {
    float u = 0.7978845608f * fmaf(0.044715f * v * v, v, v);
    float a = fabsf(u);
    float e = __expf(-2.0f * a);
    float th = __fdividef(1.0f - e, 1.0f + e);
    th = copysignf(th, u);
    return 0.5f * v * (1.0f + th);
}

// ---- module-global scratch (NOT in d_ws): fully rewritten every call ----
__device__ __align__(256) __half g_trigA[SS * 32];      // [s][32]: cos(ms) k<16 | sin(ms) k>=16
__device__ __align__(256) __half g_trigD[32 * SS];      // [m2][s]: cos rows 0-15, -sin rows 16-31
__device__ __align__(256) __half g_cwh[NL * CC * CC];   // [l][o][i]
__device__ __align__(256) __half g_fc1h[CC * CC];       // [j][w]
__device__ __align__(256) __half g_omh[BB * CC * 32];   // [b][o][32]: omr*sc(+cb at k=0) | -omi*sc
__device__ __align__(256) float  g_Xfp[BB * 16 * 32 * CC]; // 8 MB [b][p16][m2][o] fp32 DFT partials
__device__ __align__(256) float  g_Xf[BB * 32 * CC];    // [b][m2][i] (layer-0 analytic only)
__device__ __align__(256) float  g_Xx[BB * MM * 2];     // DFT of x
__device__ __align__(256) float  g_Xg[MM * 2];          // DFT of grid

// ---------------- k_prep2: fp16 weight copies + trig tables (merged) ----------------
__global__ __launch_bounds__(256) void k_prep2(const float* __restrict__ cw,
                                               const float* __restrict__ fc1_w) {
    int bi = blockIdx.x;
    int t = threadIdx.x;
    if (bi < 256) {
        int idx = bi * 256 + t;
        if (idx < NL * CC * CC) g_cwh[idx] = __float2half(cw[idx]);
        if (idx < CC * CC)      g_fc1h[idx] = __float2half(fc1_w[idx]);
    } else {
        int s = (bi - 256) * 256 + t;   // 8192
        for (int m = 0; m < MM; m++) {
            int ms = (m * s) & (SS - 1);
            float th = (float)ms * (TWO_PI / (float)SS);
            float sn, cs;
            sincosf(th, &sn, &cs);
            g_trigA[s * 32 + m]        = __float2half(cs);
            g_trigA[s * 32 + 16 + m]   = __float2half(sn);
            g_trigD[m * SS + s]        = __float2half(cs);
            g_trigD[(16 + m) * SS + s] = __float2half(-sn);
        }
    }
}

// ---------------- k_dftx: Xx[b][m] (blocks 0-31), Xg[m] (block 32) ----------------
__global__ __launch_bounds__(256) void k_dftx(const float* __restrict__ x) {
    __shared__ float red[4][MM][2];
    int blk = blockIdx.x;
    int t = threadIdx.x;
    int lane = t & 63;
    int wv = t >> 6;

    float accR[MM], accI[MM], cr[MM], ci[MM], pc[MM], ps[MM];
#pragma unroll
    for (int m = 0; m < MM; m++) {
        float sn, cs;
        sincosf((TWO_PI / (float)SS) * (float)(m * t), &sn, &cs);
        cr[m] = cs; ci[m] = -sn;
        sincosf((TWO_PI * 256.0f / (float)SS) * (float)m, &sn, &cs);
        pc[m] = cs; ps[m] = -sn;
        accR[m] = 0.f; accI[m] = 0.f;
    }
    for (int k = 0; k < 32; k++) {
        int s = t + (k << 8);
        float v = (blk < BB) ? x[(blk << 13) + s] : (float)s * (1.0f / 8191.0f);
#pragma unroll
        for (int m = 0; m < MM; m++) {
            accR[m] = fmaf(v, cr[m], accR[m]);
            accI[m] = fmaf(v, ci[m], accI[m]);
            float nc = cr[m] * pc[m] - ci[m] * ps[m];
            float ns = cr[m] * ps[m] + ci[m] * pc[m];
            cr[m] = nc; ci[m] = ns;
        }
    }
#pragma unroll
    for (int m = 0; m < MM; m++) {
#pragma unroll
        for (int off = 32; off > 0; off >>= 1) {
            accR[m] += __shfl_xor(accR[m], off, 64);
            accI[m] += __shfl_xor(accI[m], off, 64);
        }
        if (lane == 0) { red[wv][m][0] = accR[m]; red[wv][m][1] = accI[m]; }
    }
    __syncthreads();
    if (t < MM * 2) {
        int m = t >> 1, p = t & 1;
        float s = red[0][m][p] + red[1][m][p] + red[2][m][p] + red[3][m][p];
        if (blk < BB) g_Xx[(blk << 5) + (m << 1) + p] = s;
        else          g_Xg[(m << 1) + p] = s;
    }
}

// ---------------- k_xf0: analytic layer-0 Xf from fc0 affinity ----------------
__global__ __launch_bounds__(256) void k_xf0(const float* __restrict__ fc0_w,
                                             const float* __restrict__ fc0_b) {
    int n = blockIdx.x * 256 + threadIdx.x;   // B*32*128 = 131072
    int i = n & 127, m2 = (n >> 7) & 31, b = n >> 12;
    int m = m2 & 15, p = m2 >> 4;             // p=0 re, p=1 im
    float xv = g_Xx[(b << 5) + (m << 1) + p];
    float gv = g_Xg[(m << 1) + p];
    float v = fc0_w[2 * i] * xv + fc0_w[2 * i + 1] * gv;
    if (p == 0 && m == 0) v += (float)SS * fc0_b[i];
    g_Xf[(b << 12) + (m2 << 7) + i] = v;
}

// ---------------- k_mixr: fused Xfp-reduce + mode-mix -> g_omh ----------------
// grid 128: 4 blocks per b; each block reduces full Xf[b] into padded LDS, then
// computes its quarter of (o,m). l==0 reads analytic g_Xf instead of Xfp.
__global__ __launch_bounds__(256) void k_mixr(const float* __restrict__ w1_re,
                                              const float* __restrict__ w1_im,
                                              const float* __restrict__ gamma,
                                              const float* __restrict__ fwhm,
                                              const float* __restrict__ w2,
                                              const float* __restrict__ cb, int l) {
    __shared__ float geff[MM];
    __shared__ float ldsXf[32 * 132];     // stride-132 pad: phase-2 reads 2-way max
    int bi = blockIdx.x;
    int b = bi >> 2, q = bi & 3;
    int t = threadIdx.x;
    if (t < MM) {
        float g = 0.f;
        for (int k = 0; k < NUMK; k++) {
            float fw = fwhm[l * NUMK + k];
            float t1 = gamma[l * NUMK + k] * 3.14159265358979f / (fw + 1e-5f);
            float u = (float)t * (1.0f / 8230.0f) - fw;   // u[4115+m] = m/8230
            g = fmaf(w2[l * NUMK + k], expf(-t1 * t1 * u * u), g);
        }
        geff[t] = g;
    }
    // phase 1: materialize Xf[b] in LDS
    if (l == 0) {
#pragma unroll
        for (int it = 0; it < 16; it++) {
            int idx = (it << 8) + t;
            ldsXf[(idx >> 7) * 132 + (idx & 127)] = g_Xf[(b << 12) + idx];
        }
    } else {
#pragma unroll
        for (int it = 0; it < 16; it++) {
            int idx = (it << 8) + t;
            const float* p = g_Xfp + ((long)b << 16) + idx;
            float s = 0.f;
#pragma unroll
            for (int pp = 0; pp < 16; pp++) s += p[pp << 12];
            ldsXf[(idx >> 7) * 132 + (idx & 127)] = s;
        }
    }
    __syncthreads();
    // phase 2: this block's quarter of (o,m)
#pragma unroll
    for (int it = 0; it < 2; it++) {
        int n2 = (q << 9) + (it << 8) + t;
        int m = n2 & 15, o = n2 >> 4;     // o in [q*32, q*32+32)
        const float* xr = ldsXf + m * 132;
        const float* xi = ldsXf + (16 + m) * 132;
        const float* wr = w1_re + (l << 18) + (o << 4) + m;
        const float* wi = w1_im + (l << 18) + (o << 4) + m;
        float orr = 0.f, oii = 0.f;
        for (int i = 0; i < CC; i++) {
            float xrv = xr[i], xiv = xi[i];
            float wrv = wr[i << 11], wiv = wi[i << 11];
            orr = fmaf(xrv, wrv, orr); orr = fmaf(-xiv, wiv, orr);
            oii = fmaf(xrv, wiv, oii); oii = fmaf(xiv, wrv, oii);
        }
        float sc = geff[m] * (2.0f / (float)SS) * ((m == 0) ? 0.5f : 1.0f);
        float base = (m == 0) ? cb[l * CC + o] : 0.0f;   // bias rides cos(0)=1
        g_omh[(b << 12) + (o << 5) + m]      = __float2half(orr * sc + base);
        g_omh[(b << 12) + (o << 5) + 16 + m] = __float2half(-oii * sc);
    }
}

// GEMM K-step: A from swizzled LDS cw, B = two h fragments
#define GEMM_STEP(KS, HA, HB)                                                       \
    _Pragma("unroll")                                                               \
    for (int af = 0; af < 8; af++) {                                                \
        int row = (af << 4) + lr;                                                   \
        const f16x8 av = *(const f16x8*)(ldsA + (row << 8) +                        \
                          ((((KS << 2) + lg) ^ (row & 7)) << 4));                   \
        acc[af][0] = MFMA16(av, HA, acc[af][0]);                                    \
        acc[af][1] = MFMA16(av, HB, acc[af][1]);                                    \
    }

#define LOAD_HF(S0X)                                                                \
    {                                                                               \
        int hr = (((b << 13) + (S0X) + (wid << 5) + lr) << 8) + (lg << 4);          \
        hf0 = *(const f16x8*)(h_c + hr);                                            \
        hf1 = *(const f16x8*)(h_c + hr + (16 << 8));                                \
        hf2 = *(const f16x8*)(h_c + hr + (1 << 6));                                 \
        hf3 = *(const f16x8*)(h_c + hr + (16 << 8) + (1 << 6));                     \
        hf4 = *(const f16x8*)(h_c + hr + (2 << 6));                                 \
        hf5 = *(const f16x8*)(h_c + hr + (16 << 8) + (2 << 6));                     \
        hf6 = *(const f16x8*)(h_c + hr + (3 << 6));                                 \
        hf7 = *(const f16x8*)(h_c + hr + (16 << 8) + (3 << 6));                     \
    }

#define LOAD_TF(S0X)                                                                \
    {                                                                               \
        int tr2 = (((S0X) + (wid << 5) + lr) << 6) + (lg << 4);                     \
        tf0 = *(const f16x8*)(ta_c + tr2);                                          \
        tf1 = *(const f16x8*)(ta_c + tr2 + (16 << 6));                              \
    }

// ---------------- k_layer: persistent 4-tile block, barrier-free per-wave DFT ----
// SRC=1 (layer 0): B-operand computed in-register from x via fc0 affinity (no k_fc0).
// Always TAIL behavior: gelu + stash + DFT + block tree-reduce -> 16 Xfp partials.
template <int SRC>
__global__ __launch_bounds__(256, 2) void k_layer(__half* __restrict__ h,
                                                  const float* __restrict__ x,
                                                  const float* __restrict__ fc0_w,
                                                  const float* __restrict__ fc0_b, int l) {
    __shared__ __align__(16) char smem[73728];
    char* ldsA = smem;                               // 32 KB cw, swizzled
    char* ldsO = smem + 32768;                       // 8 KB om, swizzled
    char* ldsS = smem + 40960;                       // 32 KB stash: 4 x 8 KB wave strips
    int bi = blockIdx.x;
    int b = bi >> 4, grp = bi & 15;
    int Sg = grp << 9;                               // 512 s per block
    int t = threadIdx.x;
    int wid = __builtin_amdgcn_readfirstlane(t >> 6);
    int l6 = t & 63, lr = l6 & 15, lg = l6 >> 4;
    const char* h_c = (const char*)h;
    char* hw = (char*)h;
    const char* cw_c = (const char*)(g_cwh + l * CC * CC);
    const char* om_c = (const char*)(g_omh + (b << 12));
    const char* ta_c = (const char*)g_trigA;
    const char* td_c = (const char*)g_trigD;
    char* strip = ldsS + (wid << 13);                // this wave's private 8 KB

    // stage cw -> ldsA (both-sides swizzle: slot = c16 ^ (row&7))
#pragma unroll
    for (int k = 0; k < 8; k++) {
        int c = (k << 8) + t;                        // 0..2047 chunks of 16 B
        f16x8 v = *(const f16x8*)(cw_c + (c << 4));
        int row = c >> 4, c16 = c & 15;
        *(f16x8*)(ldsA + (row << 8) + ((c16 ^ (row & 7)) << 4)) = v;
    }
    // stage om -> ldsO (slot = c4 ^ (row&3))
#pragma unroll
    for (int k = 0; k < 2; k++) {
        int c = (k << 8) + t;                        // 0..511
        f16x8 v = *(const f16x8*)(om_c + (c << 4));
        int row = c >> 2, c4 = c & 3;
        *(f16x8*)(ldsO + (row << 6) + ((c4 ^ (row & 3)) << 4)) = v;
    }
    f16x8 hf0, hf1, hf2, hf3, hf4, hf5, hf6, hf7, tf0, tf1;
    union HU { __half2 q[4]; f16x8 v; };
    HU c0[4], c1[4], cbh[4];
    float xv0 = 0.f, xv1 = 0.f;
    if (SRC) {   // fc0 coefficients for this thread's 32 channels (i = ks*32+lg*8..+7)
#pragma unroll
        for (int ks = 0; ks < 4; ks++) {
            int i0 = (ks << 5) + (lg << 3);
            const float* wp = fc0_w + (i0 << 1);
            float4 a  = *(const float4*)(wp);
            float4 bq = *(const float4*)(wp + 4);
            float4 cq = *(const float4*)(wp + 8);
            float4 dq = *(const float4*)(wp + 12);
            c0[ks].q[0] = __floats2half2_rn(a.x, a.z);   c1[ks].q[0] = __floats2half2_rn(a.y, a.w);
            c0[ks].q[1] = __floats2half2_rn(bq.x, bq.z); c1[ks].q[1] = __floats2half2_rn(bq.y, bq.w);
            c0[ks].q[2] = __floats2half2_rn(cq.x, cq.z); c1[ks].q[2] = __floats2half2_rn(cq.y, cq.w);
            c0[ks].q[3] = __floats2half2_rn(dq.x, dq.z); c1[ks].q[3] = __floats2half2_rn(dq.y, dq.w);
            float4 e = *(const float4*)(fc0_b + i0);
            float4 f = *(const float4*)(fc0_b + i0 + 4);
            cbh[ks].q[0] = __floats2half2_rn(e.x, e.y);
            cbh[ks].q[1] = __floats2half2_rn(e.z, e.w);
            cbh[ks].q[2] = __floats2half2_rn(f.x, f.y);
            cbh[ks].q[3] = __floats2half2_rn(f.z, f.w);
        }
        xv0 = x[(b << 13) + Sg + (wid << 5) + lr];
        xv1 = x[(b << 13) + Sg + (wid << 5) + 16 + lr];
    } else {
        LOAD_HF(Sg)
    }
    LOAD_TF(Sg)
    __syncthreads();

    f32x4 dacc[8][2];                                // DFT partial, accumulated over 4 tiles
#pragma unroll
    for (int af = 0; af < 8; af++) {
        dacc[af][0] = (f32x4){0.f, 0.f, 0.f, 0.f};
        dacc[af][1] = (f32x4){0.f, 0.f, 0.f, 0.f};
    }

    for (int ti = 0; ti < 4; ti++) {
        int S0 = Sg + (ti << 7);
        if (SRC) {   // compute B-frags from x (fc0 affine), fp16 pk-fma
            int sA = S0 + (wid << 5) + lr;
            __half2 xx0 = __floats2half2_rn(xv0, xv0);
            __half2 xx1 = __floats2half2_rn(xv1, xv1);
            float gv0 = (float)sA * (1.0f / 8191.0f);
            float gv1 = (float)(sA + 16) * (1.0f / 8191.0f);
            __half2 gg0 = __floats2half2_rn(gv0, gv0);
            __half2 gg1 = __floats2half2_rn(gv1, gv1);
#pragma unroll
            for (int ks = 0; ks < 4; ks++) {
                HU r0, r1;
#pragma unroll
                for (int q = 0; q < 4; q++) {
                    r0.q[q] = __hfma2(c0[ks].q[q], xx0, __hfma2(c1[ks].q[q], gg0, cbh[ks].q[q]));
                    r1.q[q] = __hfma2(c0[ks].q[q], xx1, __hfma2(c1[ks].q[q], gg1, cbh[ks].q[q]));
                }
                if (ks == 0)      { hf0 = r0.v; hf1 = r1.v; }
                else if (ks == 1) { hf2 = r0.v; hf3 = r1.v; }
                else if (ks == 2) { hf4 = r0.v; hf5 = r1.v; }
                else              { hf6 = r0.v; hf7 = r1.v; }
            }
        }
        f32x4 acc[8][2];
#pragma unroll
        for (int af = 0; af < 8; af++) {
            acc[af][0] = (f32x4){0.f, 0.f, 0.f, 0.f};
            acc[af][1] = (f32x4){0.f, 0.f, 0.f, 0.f};
        }
        __builtin_amdgcn_s_setprio(1);
        GEMM_STEP(0, hf0, hf1)
        GEMM_STEP(1, hf2, hf3)
        GEMM_STEP(2, hf4, hf5)
        GEMM_STEP(3, hf6, hf7)
#pragma unroll
        for (int af = 0; af < 8; af++) {             // irfft K-step (+bias at k=0)
            int row = (af << 4) + lr;
            const f16x8 ov = *(const f16x8*)(ldsO + (row << 6) + ((lg ^ (row & 3)) << 4));
            acc[af][0] = MFMA16(ov, tf0, acc[af][0]);
            acc[af][1] = MFMA16(ov, tf1, acc[af][1]);
        }
        __builtin_amdgcn_s_setprio(0);
        if (ti < 3) {                                // prefetch next tile's operands
            int S0n = S0 + 128;
            if (SRC) {
                xv0 = x[(b << 13) + S0n + (wid << 5) + lr];
                xv1 = x[(b << 13) + S0n + (wid << 5) + 16 + lr];
            } else {
                LOAD_HF(S0n)
            }
            LOAD_TF(S0n)
        }
        // current tile's trigD fragments — latency hidden under the gelu epilogue
        f16x8 td0, td1;
        {
            int sgl = S0 + (wid << 5) + (lg << 3);
            td0 = *(const f16x8*)(td_c + (((lr << 13) + sgl) << 1));
            td1 = *(const f16x8*)(td_c + ((((16 + lr) << 13) + sgl) << 1));
        }
#pragma unroll
        for (int bf = 0; bf < 2; bf++) {
            int s_w = (bf << 4) + lr;                // s within this wave's 32
            int s = S0 + (wid << 5) + s_w;
#pragma unroll
            for (int af = 0; af < 8; af++) {
                int o0 = (af << 4) + (lg << 2);
                float v0 = gelu_f(acc[af][bf][0]), v1 = gelu_f(acc[af][bf][1]);
                float v2 = gelu_f(acc[af][bf][2]), v3 = gelu_f(acc[af][bf][3]);
                union { __half2 q[2]; unsigned long long u; } pk;
                pk.q[0] = __floats2half2_rn(v0, v1);
                pk.q[1] = __floats2half2_rn(v2, v3);
                *(unsigned long long*)(hw + (((b << 13) + s) << 8) + (o0 << 1)) = pk.u;
                int byte = (s_w << 8) + ((o0 << 1) ^ ((s_w & 15) << 4));
                *(unsigned long long*)(strip + byte) = pk.u;
            }
        }
        asm volatile("s_waitcnt lgkmcnt(0)" ::: "memory");
        __builtin_amdgcn_sched_barrier(0);
        // per-wave DFT partial over this wave's 32 s (no block barrier)
#pragma unroll
        for (int af = 0; af < 8; af++) {
            int o = (af << 4) + lr;
            union { unsigned int u[4]; f16x8 v; } bb;
#pragma unroll
            for (int p = 0; p < 4; p++) {
                int s0 = (lg << 3) + 2 * p, s1 = s0 + 1;
                unsigned int lo = *(const unsigned short*)
                    (strip + (s0 << 8) + ((o << 1) ^ ((s0 & 15) << 4)));
                unsigned int hi = *(const unsigned short*)
                    (strip + (s1 << 8) + ((o << 1) ^ ((s1 & 15) << 4)));
                bb.u[p] = lo | (hi << 16);
            }
            dacc[af][0] = MFMA16(td0, bb.v, dacc[af][0]);
            dacc[af][1] = MFMA16(td1, bb.v, dacc[af][1]);
        }
    }
    {   // block tree-reduce dacc in the (now dead) stash -> 1 partial per grp
        float* red = (float*)ldsS;
        __syncthreads();
        if (wid == 1 || wid == 3) {
            float* rp = red + ((wid >> 1) << 12) + l6;
#pragma unroll
            for (int af = 0; af < 8; af++)
#pragma unroll
                for (int mh = 0; mh < 2; mh++)
#pragma unroll
                    for (int reg = 0; reg < 4; reg++)
                        rp[((af << 3) + (mh << 2) + reg) << 6] = dacc[af][mh][reg];
        }
        __syncthreads();
        if (wid == 0 || wid == 2) {
            const float* rp = red + ((wid >> 1) << 12) + l6;
#pragma unroll
            for (int af = 0; af < 8; af++)
#pragma unroll
                for (int mh = 0; mh < 2; mh++)
#pragma unroll
                    for (int reg = 0; reg < 4; reg++)
                        dacc[af][mh][reg] += rp[((af << 3) + (mh << 2) + reg) << 6];
        }
        __syncthreads();
        if (wid == 2) {
            float* rp = red + l6;
#pragma unroll
            for (int af = 0; af < 8; af++)
#pragma unroll
                for (int mh = 0; mh < 2; mh++)
#pragma unroll
                    for (int reg = 0; reg < 4; reg++)
                        rp[((af << 3) + (mh << 2) + reg) << 6] = dacc[af][mh][reg];
        }
        __syncthreads();
        if (wid == 0) {
            const float* rp = red + l6;
            float* xp = g_Xfp + (((long)(b << 4) + grp) << 12);
#pragma unroll
            for (int af = 0; af < 8; af++)
#pragma unroll
                for (int mh = 0; mh < 2; mh++)
#pragma unroll
                    for (int reg = 0; reg < 4; reg++) {
                        float v = dacc[af][mh][reg] + rp[((af << 3) + (mh << 2) + reg) << 6];
                        int m2 = (mh << 4) + (lg << 2) + reg;
                        int o = (af << 4) + lr;
                        xp[(m2 << 7) + o] = v;
                    }
        }
    }
}

// ---------------- k_tail: l=3 conv+irfft fused with fc1/gelu/fc2 head ----------------
__global__ __launch_bounds__(256, 2) void k_tail(const __half* __restrict__ h,
                                                 const float* __restrict__ fc1_b,
                                                 const float* __restrict__ fc2_w,
                                                 const float* __restrict__ fc2_b,
                                                 float* __restrict__ out) {
    __shared__ __align__(16) char smem[73728];
    char* ldsA = smem;                               // 32 KB cw(l=3), swizzled
    char* ldsO = smem + 32768;                       // 8 KB om, swizzled
    char* ldsS = smem + 40960;                       // 32 KB stash
    int bi = blockIdx.x;
    int b = bi >> 4, grp = bi & 15;
    int Sg = grp << 9;
    int t = threadIdx.x;
    int wid = __builtin_amdgcn_readfirstlane(t >> 6);
    int l6 = t & 63, lr = l6 & 15, lg = l6 >> 4;
    const char* h_c = (const char*)h;
    const char* cw_c = (const char*)(g_cwh + 3 * CC * CC);
    const char* om_c = (const char*)(g_omh + (b << 12));
    const char* ta_c = (const char*)g_trigA;
    const char* f1_c = (const char*)g_fc1h;
    char* strip = ldsS + (wid << 13);

#pragma unroll
    for (int k = 0; k < 8; k++) {
        int c = (k << 8) + t;
        f16x8 v = *(const f16x8*)(cw_c + (c << 4));
        int row = c >> 4, c16 = c & 15;
        *(f16x8*)(ldsA + (row << 8) + ((c16 ^ (row & 7)) << 4)) = v;
    }
#pragma unroll
    for (int k = 0; k < 2; k++) {
        int c = (k << 8) + t;
        f16x8 v = *(const f16x8*)(om_c + (c << 4));
        int row = c >> 2, c4 = c & 3;
        *(f16x8*)(ldsO + (row << 6) + ((c4 ^ (row & 3)) << 4)) = v;
    }
    f16x8 hf0, hf1, hf2, hf3, hf4, hf5, hf6, hf7, tf0, tf1;
    LOAD_HF(Sg)
    LOAD_TF(Sg)
    __syncthreads();

    float f2b = fc2_b[0];
    for (int ti = 0; ti < 4; ti++) {
        int S0 = Sg + (ti << 7);
        {   // ---- GEMM1: conv1x1 + irfft (no gelu; l=3) -> stash ----
            f32x4 acc[8][2];
#pragma unroll
            for (int af = 0; af < 8; af++) {
                acc[af][0] = (f32x4){0.f, 0.f, 0.f, 0.f};
                acc[af][1] = (f32x4){0.f, 0.f, 0.f, 0.f};
            }
            __builtin_amdgcn_s_setprio(1);
            GEMM_STEP(0, hf0, hf1)
            GEMM_STEP(1, hf2, hf3)
            GEMM_STEP(2, hf4, hf5)
            GEMM_STEP(3, hf6, hf7)
#pragma unroll
            for (int af = 0; af < 8; af++) {
                int row = (af << 4) + lr;
                const f16x8 ov = *(const f16x8*)(ldsO + (row << 6) + ((lg ^ (row & 3)) << 4));
                acc[af][0] = MFMA16(ov, tf0, acc[af][0]);
                acc[af][1] = MFMA16(ov, tf1, acc[af][1]);
            }
            __builtin_amdgcn_s_setprio(0);
            if (ti < 3) {
                int S0n = S0 + 128;
                LOAD_HF(S0n)
                LOAD_TF(S0n)
            }
#pragma unroll
            for (int bf = 0; bf < 2; bf++) {
                int s_w = (bf << 4) + lr;
#pragma unroll
                for (int af = 0; af < 8; af++) {
                    int o0 = (af << 4) + (lg << 2);
                    union { __half2 q[2]; unsigned long long u; } pk;
                    pk.q[0] = __floats2half2_rn(acc[af][bf][0], acc[af][bf][1]);
                    pk.q[1] = __floats2half2_rn(acc[af][bf][2], acc[af][bf][3]);
                    int byte = (s_w << 8) + ((o0 << 1) ^ ((s_w & 15) << 4));
                    *(unsigned long long*)(strip + byte) = pk.u;
                }
            }
        }
        asm volatile("s_waitcnt lgkmcnt(0)" ::: "memory");
        __builtin_amdgcn_sched_barrier(0);
        {   // ---- GEMM2: fc1 (A from L2), B = one swizzled b128 slot per (ks,bf) ----
            f32x4 acc2[8][2];
#pragma unroll
            for (int af = 0; af < 8; af++) {
                acc2[af][0] = (f32x4){0.f, 0.f, 0.f, 0.f};
                acc2[af][1] = (f32x4){0.f, 0.f, 0.f, 0.f};
            }
#pragma unroll
            for (int ks = 0; ks < 4; ks++) {
#pragma unroll
                for (int bf = 0; bf < 2; bf++) {
                    int s_loc = (bf << 4) + lr;
                    int obyte = (((ks << 5) + (lg << 3)) << 1) ^ ((s_loc & 15) << 4);
                    const f16x8 bv = *(const f16x8*)(strip + (s_loc << 8) + obyte);
#pragma unroll
                    for (int af = 0; af < 8; af++) {
                        const f16x8 av = *(const f16x8*)
                            (f1_c + (((af << 4) + lr) << 8) + (ks << 6) + (lg << 4));
                        acc2[af][bf] = MFMA16(av, bv, acc2[af][bf]);
                    }
                }
            }
            float p[2] = {0.f, 0.f};
#pragma unroll
            for (int af = 0; af < 8; af++) {
                float4 fb = *(const float4*)(fc1_b + (af << 4) + (lg << 2));
                float4 f2 = *(const float4*)(fc2_w + (af << 4) + (lg << 2));
#pragma unroll
                for (int bf = 0; bf < 2; bf++) {
                    float v0 = gelu_f(acc2[af][bf][0] + fb.x);
                    float v1 = gelu_f(acc2[af][bf][1] + fb.y);
                    float v2 = gelu_f(acc2[af][bf][2] + fb.z);
                    float v3 = gelu_f(acc2[af][bf][3] + fb.w);
                    p[bf] += f2.x * v0 + f2.y * v1 + f2.z * v2 + f2.w * v3;
                }
            }
#pragma unroll
            for (int bf = 0; bf < 2; bf++) {
                float v = p[bf];
                v += __shfl_xor(v, 16, 64);
                v += __shfl_xor(v, 32, 64);
                if (lg == 0) out[(b << 13) + S0 + (wid << 5) + (bf << 4) + lr] = v + f2b;
            }
        }
    }
}

extern "C" void kernel_launch(void* const* d_in, const int* in_sizes, int n_in,
                              void* d_out, int out_size, void* d_ws, size_t ws_size,
                              hipStream_t stream) {
    const float* x      = (const float*)d_in[0];
    const float* w1_re  = (const float*)d_in[1];
    const float* w1_im  = (const float*)d_in[2];
    const float* gamma  = (const float*)d_in[3];
    const float* fwhm   = (const float*)d_in[4];
    const float* w2     = (const float*)d_in[5];
    const float* cw     = (const float*)d_in[6];
    const float* cb     = (const float*)d_in[7];
    const float* fc0_w  = (const float*)d_in[8];
    const float* fc0_b  = (const float*)d_in[9];
    const float* fc1_w  = (const float*)d_in[10];
    const float* fc1_b  = (const float*)d_in[11];
    const float* fc2_w  = (const float*)d_in[12];
    const float* fc2_b  = (const float*)d_in[13];
    float* out = (float*)d_out;

    __half* h = (__half*)d_ws;                      // 64 MiB, [b][s][i]

    k_prep2<<<dim3(288), dim3(256), 0, stream>>>(cw, fc1_w);
    k_dftx<<<dim3(33), dim3(256), 0, stream>>>(x);
    k_xf0<<<dim3(512), dim3(256), 0, stream>>>(fc0_w, fc0_b);
    for (int l = 0; l < NL; l++) {
        k_mixr<<<dim3(128), dim3(256), 0, stream>>>(w1_re, w1_im, gamma, fwhm, w2, cb, l);
        if (l == 0) {
            k_layer<1><<<dim3(512), dim3(256), 0, stream>>>(h, x, fc0_w, fc0_b, l);
        } else if (l < NL - 1) {
            k_layer<0><<<dim3(512), dim3(256), 0, stream>>>(h, x, fc0_w, fc0_b, l);
        } else {
            k_tail<<<dim3(512), dim3(256), 0, stream>>>(h, fc1_b, fc2_w, fc2_b, out);
        }
    }
}

// Round 21
// 307.162 us; speedup vs baseline: 1.1208x; 1.1208x over previous
//
#include <hip/hip_runtime.h>
#include <hip/hip_fp16.h>

#define BB 32
#define SS 8192
#define CC 128
#define MM 16
#define NUMK 8
#define NL 4

#define TWO_PI 6.2831853071795864769f

typedef _Float16 f16x8 __attribute__((ext_vector_type(8)));
typedef float f32x4 __attribute__((ext_vector_type(4)));

#define MFMA16(a, b, c) __builtin_amdgcn_mfma_f32_16x16x32_f16((a), (b), (c), 0, 0, 0)

// tanh-form GELU (max dev from exact erf-GELU ~3e-4, threshold 1.9e-2)
__device__ __forceinline__ float gelu_f(float v) {
    float u = 0.7978845608f * fmaf(0.044715f * v * v, v, v);
    float a = fabsf(u);
    float e = __expf(-2.0f * a);
    float th = __fdividef(1.0f - e, 1.0f + e);
    th = copysignf(th, u);
    return 0.5f * v * (1.0f + th);
}

// ---- module-global scratch (NOT in d_ws): fully rewritten every call ----
__device__ __align__(256) __half g_trigA[SS * 32];      // [s][32]: cos(ms) k<16 | sin(ms) k>=16
__device__ __align__(256) __half g_trigD[32 * SS];      // [m2][s]: cos rows 0-15, -sin rows 16-31
__device__ __align__(256) __half g_cwh[NL * CC * CC];   // [l][o][i]
__device__ __align__(256) __half g_fc1h[CC * CC];       // [j][w]
__device__ __align__(256) __half g_omh[BB * CC * 32];   // [b][o][32]: omr*sc(+cb at k=0) | -omi*sc
__device__ __align__(256) float  g_Xfp[BB * 16 * 32 * CC]; // 8 MB [b][p16][m2][o] fp32 DFT partials
__device__ __align__(256) float  g_Xf[BB * 32 * CC];    // [b][m2][i]
__device__ __align__(256) float  g_Xx[BB * MM * 2];     // DFT of x
__device__ __align__(256) float  g_Xg[MM * 2];          // DFT of grid

// ---------------- k_prep2: fp16 weight copies + trig tables (merged) ----------------
__global__ __launch_bounds__(256) void k_prep2(const float* __restrict__ cw,
                                               const float* __restrict__ fc1_w) {
    int bi = blockIdx.x;
    int t = threadIdx.x;
    if (bi < 256) {
        int idx = bi * 256 + t;
        if (idx < NL * CC * CC) g_cwh[idx] = __float2half(cw[idx]);
        if (idx < CC * CC)      g_fc1h[idx] = __float2half(fc1_w[idx]);
    } else {
        int s = (bi - 256) * 256 + t;   // 8192
        for (int m = 0; m < MM; m++) {
            int ms = (m * s) & (SS - 1);
            float th = (float)ms * (TWO_PI / (float)SS);
            float sn, cs;
            sincosf(th, &sn, &cs);
            g_trigA[s * 32 + m]        = __float2half(cs);
            g_trigA[s * 32 + 16 + m]   = __float2half(sn);
            g_trigD[m * SS + s]        = __float2half(cs);
            g_trigD[(16 + m) * SS + s] = __float2half(-sn);
        }
    }
}

// ---------------- k_dftx: Xx[b][m] (blocks 0-31), Xg[m] (block 32) ----------------
__global__ __launch_bounds__(256) void k_dftx(const float* __restrict__ x) {
    __shared__ float red[4][MM][2];
    int blk = blockIdx.x;
    int t = threadIdx.x;
    int lane = t & 63;
    int wv = t >> 6;

    float accR[MM], accI[MM], cr[MM], ci[MM], pc[MM], ps[MM];
#pragma unroll
    for (int m = 0; m < MM; m++) {
        float sn, cs;
        sincosf((TWO_PI / (float)SS) * (float)(m * t), &sn, &cs);
        cr[m] = cs; ci[m] = -sn;
        sincosf((TWO_PI * 256.0f / (float)SS) * (float)m, &sn, &cs);
        pc[m] = cs; ps[m] = -sn;
        accR[m] = 0.f; accI[m] = 0.f;
    }
    for (int k = 0; k < 32; k++) {
        int s = t + (k << 8);
        float v = (blk < BB) ? x[(blk << 13) + s] : (float)s * (1.0f / 8191.0f);
#pragma unroll
        for (int m = 0; m < MM; m++) {
            accR[m] = fmaf(v, cr[m], accR[m]);
            accI[m] = fmaf(v, ci[m], accI[m]);
            float nc = cr[m] * pc[m] - ci[m] * ps[m];
            float ns = cr[m] * ps[m] + ci[m] * pc[m];
            cr[m] = nc; ci[m] = ns;
        }
    }
#pragma unroll
    for (int m = 0; m < MM; m++) {
#pragma unroll
        for (int off = 32; off > 0; off >>= 1) {
            accR[m] += __shfl_xor(accR[m], off, 64);
            accI[m] += __shfl_xor(accI[m], off, 64);
        }
        if (lane == 0) { red[wv][m][0] = accR[m]; red[wv][m][1] = accI[m]; }
    }
    __syncthreads();
    if (t < MM * 2) {
        int m = t >> 1, p = t & 1;
        float s = red[0][m][p] + red[1][m][p] + red[2][m][p] + red[3][m][p];
        if (blk < BB) g_Xx[(blk << 5) + (m << 1) + p] = s;
        else          g_Xg[(m << 1) + p] = s;
    }
}

// ---------------- k_xf0: analytic layer-0 Xf from fc0 affinity ----------------
__global__ __launch_bounds__(256) void k_xf0(const float* __restrict__ fc0_w,
                                             const float* __restrict__ fc0_b) {
    int n = blockIdx.x * 256 + threadIdx.x;   // B*32*128 = 131072
    int i = n & 127, m2 = (n >> 7) & 31, b = n >> 12;
    int m = m2 & 15, p = m2 >> 4;             // p=0 re, p=1 im
    float xv = g_Xx[(b << 5) + (m << 1) + p];
    float gv = g_Xg[(m << 1) + p];
    float v = fc0_w[2 * i] * xv + fc0_w[2 * i + 1] * gv;
    if (p == 0 && m == 0) v += (float)SS * fc0_b[i];
    g_Xf[(b << 12) + (m2 << 7) + i] = v;
}

// ---------------- k_red2: g_Xf[b][m2][i] = sum_p g_Xfp (16 partials) ----------------
__global__ __launch_bounds__(256) void k_red2() {
    int n = blockIdx.x * 256 + threadIdx.x;   // 131072
    int i = n & 127, m2 = (n >> 7) & 31, b = n >> 12;
    const float* p = g_Xfp + ((long)b << 16) + (m2 << 7) + i;
    float s = 0.f;
#pragma unroll 8
    for (int t = 0; t < 16; t++) s += p[t << 12];
    g_Xf[(b << 12) + (m2 << 7) + i] = s;
}

// ---------------- k_mix: block-coalesced w1 reads (original layout) ----------------
__global__ __launch_bounds__(256) void k_mix(const float* __restrict__ w1_re,
                                             const float* __restrict__ w1_im,
                                             const float* __restrict__ gamma,
                                             const float* __restrict__ fwhm,
                                             const float* __restrict__ w2,
                                             const float* __restrict__ cb, int l) {
    __shared__ float geff[MM];
    int t = threadIdx.x;
    if (t < MM) {
        float g = 0.f;
        for (int k = 0; k < NUMK; k++) {
            float fw = fwhm[l * NUMK + k];
            float t1 = gamma[l * NUMK + k] * 3.14159265358979f / (fw + 1e-5f);
            float u = (float)t * (1.0f / 8230.0f) - fw;   // u[4115+m] = m/8230
            g = fmaf(w2[l * NUMK + k], expf(-t1 * t1 * u * u), g);
        }
        geff[t] = g;
    }
    __syncthreads();

    int n = blockIdx.x * 256 + t;    // over B*C*M = 65536
    int m = n & 15, o = (n >> 4) & 127, b = n >> 11;
    const float* xr = g_Xf + (b << 12) + (m << 7);
    const float* xi = g_Xf + (b << 12) + ((16 + m) << 7);
    const float* wr = w1_re + (l << 18) + (o << 4) + m;
    const float* wi = w1_im + (l << 18) + (o << 4) + m;
    float orr = 0.f, oii = 0.f;
    for (int i = 0; i < CC; i++) {
        float xrv = xr[i], xiv = xi[i];
        float wrv = wr[i << 11], wiv = wi[i << 11];
        orr = fmaf(xrv, wrv, orr); orr = fmaf(-xiv, wiv, orr);
        oii = fmaf(xrv, wiv, oii); oii = fmaf(xiv, wrv, oii);
    }
    float sc = geff[m] * (2.0f / (float)SS) * ((m == 0) ? 0.5f : 1.0f);
    float base = (m == 0) ? cb[l * CC + o] : 0.0f;   // bias rides the cos(0)=1 column
    g_omh[(b << 12) + (o << 5) + m]      = __float2half(orr * sc + base);
    g_omh[(b << 12) + (o << 5) + 16 + m] = __float2half(-oii * sc);
}

// GEMM K-step: A from swizzled LDS cw, B = two h fragments
#define GEMM_STEP(KS, HA, HB)                                                       \
    _Pragma("unroll")                                                               \
    for (int af = 0; af < 8; af++) {                                                \
        int row = (af << 4) + lr;                                                   \
        const f16x8 av = *(const f16x8*)(ldsA + (row << 8) +                        \
                          ((((KS << 2) + lg) ^ (row & 7)) << 4));                   \
        acc[af][0] = MFMA16(av, HA, acc[af][0]);                                    \
        acc[af][1] = MFMA16(av, HB, acc[af][1]);                                    \
    }

#define LOAD_HF(S0X)                                                                \
    {                                                                               \
        int hr = (((b << 13) + (S0X) + (wid << 5) + lr) << 8) + (lg << 4);          \
        hf0 = *(const f16x8*)(h_c + hr);                                            \
        hf1 = *(const f16x8*)(h_c + hr + (16 << 8));                                \
        hf2 = *(const f16x8*)(h_c + hr + (1 << 6));                                 \
        hf3 = *(const f16x8*)(h_c + hr + (16 << 8) + (1 << 6));                     \
        hf4 = *(const f16x8*)(h_c + hr + (2 << 6));                                 \
        hf5 = *(const f16x8*)(h_c + hr + (16 << 8) + (2 << 6));                     \
        hf6 = *(const f16x8*)(h_c + hr + (3 << 6));                                 \
        hf7 = *(const f16x8*)(h_c + hr + (16 << 8) + (3 << 6));                     \
    }

#define LOAD_TF(S0X)                                                                \
    {                                                                               \
        int tr2 = (((S0X) + (wid << 5) + lr) << 6) + (lg << 4);                     \
        tf0 = *(const f16x8*)(ta_c + tr2);                                          \
        tf1 = *(const f16x8*)(ta_c + tr2 + (16 << 6));                              \
    }

// ---------------- k_layer: persistent 4-tile block, barrier-free per-wave DFT ----
// SRC=1 (layer 0): B-operand computed in-register from x via fc0 affinity (no k_fc0).
// Always TAIL behavior: gelu + stash + DFT + block tree-reduce -> 16 Xfp partials.
template <int SRC>
__global__ __launch_bounds__(256, 2) void k_layer(__half* __restrict__ h,
                                                  const float* __restrict__ x,
                                                  const float* __restrict__ fc0_w,
                                                  const float* __restrict__ fc0_b, int l) {
    __shared__ __align__(16) char smem[73728];
    char* ldsA = smem;                               // 32 KB cw, swizzled
    char* ldsO = smem + 32768;                       // 8 KB om, swizzled
    char* ldsS = smem + 40960;                       // 32 KB stash: 4 x 8 KB wave strips
    int bi = blockIdx.x;
    int b = bi >> 4, grp = bi & 15;
    int Sg = grp << 9;                               // 512 s per block
    int t = threadIdx.x;
    int wid = __builtin_amdgcn_readfirstlane(t >> 6);
    int l6 = t & 63, lr = l6 & 15, lg = l6 >> 4;
    const char* h_c = (const char*)h;
    char* hw = (char*)h;
    const char* cw_c = (const char*)(g_cwh + l * CC * CC);
    const char* om_c = (const char*)(g_omh + (b << 12));
    const char* ta_c = (const char*)g_trigA;
    const char* td_c = (const char*)g_trigD;
    char* strip = ldsS + (wid << 13);                // this wave's private 8 KB

    // stage cw -> ldsA (both-sides swizzle: slot = c16 ^ (row&7))
#pragma unroll
    for (int k = 0; k < 8; k++) {
        int c = (k << 8) + t;                        // 0..2047 chunks of 16 B
        f16x8 v = *(const f16x8*)(cw_c + (c << 4));
        int row = c >> 4, c16 = c & 15;
        *(f16x8*)(ldsA + (row << 8) + ((c16 ^ (row & 7)) << 4)) = v;
    }
    // stage om -> ldsO (slot = c4 ^ (row&3))
#pragma unroll
    for (int k = 0; k < 2; k++) {
        int c = (k << 8) + t;                        // 0..511
        f16x8 v = *(const f16x8*)(om_c + (c << 4));
        int row = c >> 2, c4 = c & 3;
        *(f16x8*)(ldsO + (row << 6) + ((c4 ^ (row & 3)) << 4)) = v;
    }
    f16x8 hf0, hf1, hf2, hf3, hf4, hf5, hf6, hf7, tf0, tf1;
    union HU { __half2 q[4]; f16x8 v; };
    HU c0[4], c1[4], cbh[4];
    float xv0 = 0.f, xv1 = 0.f;
    if (SRC) {   // fc0 coefficients for this thread's 32 channels (i = ks*32+lg*8..+7)
#pragma unroll
        for (int ks = 0; ks < 4; ks++) {
            int i0 = (ks << 5) + (lg << 3);
            const float* wp = fc0_w + (i0 << 1);
            float4 a  = *(const float4*)(wp);
            float4 bq = *(const float4*)(wp + 4);
            float4 cq = *(const float4*)(wp + 8);
            float4 dq = *(const float4*)(wp + 12);
            c0[ks].q[0] = __floats2half2_rn(a.x, a.z);   c1[ks].q[0] = __floats2half2_rn(a.y, a.w);
            c0[ks].q[1] = __floats2half2_rn(bq.x, bq.z); c1[ks].q[1] = __floats2half2_rn(bq.y, bq.w);
            c0[ks].q[2] = __floats2half2_rn(cq.x, cq.z); c1[ks].q[2] = __floats2half2_rn(cq.y, cq.w);
            c0[ks].q[3] = __floats2half2_rn(dq.x, dq.z); c1[ks].q[3] = __floats2half2_rn(dq.y, dq.w);
            float4 e = *(const float4*)(fc0_b + i0);
            float4 f = *(const float4*)(fc0_b + i0 + 4);
            cbh[ks].q[0] = __floats2half2_rn(e.x, e.y);
            cbh[ks].q[1] = __floats2half2_rn(e.z, e.w);
            cbh[ks].q[2] = __floats2half2_rn(f.x, f.y);
            cbh[ks].q[3] = __floats2half2_rn(f.z, f.w);
        }
        xv0 = x[(b << 13) + Sg + (wid << 5) + lr];
        xv1 = x[(b << 13) + Sg + (wid << 5) + 16 + lr];
    } else {
        LOAD_HF(Sg)
    }
    LOAD_TF(Sg)
    __syncthreads();

    f32x4 dacc[8][2];                                // DFT partial, accumulated over 4 tiles
#pragma unroll
    for (int af = 0; af < 8; af++) {
        dacc[af][0] = (f32x4){0.f, 0.f, 0.f, 0.f};
        dacc[af][1] = (f32x4){0.f, 0.f, 0.f, 0.f};
    }

    for (int ti = 0; ti < 4; ti++) {
        int S0 = Sg + (ti << 7);
        if (SRC) {   // compute B-frags from x (fc0 affine), fp16 pk-fma
            int sA = S0 + (wid << 5) + lr;
            __half2 xx0 = __floats2half2_rn(xv0, xv0);
            __half2 xx1 = __floats2half2_rn(xv1, xv1);
            float gv0 = (float)sA * (1.0f / 8191.0f);
            float gv1 = (float)(sA + 16) * (1.0f / 8191.0f);
            __half2 gg0 = __floats2half2_rn(gv0, gv0);
            __half2 gg1 = __floats2half2_rn(gv1, gv1);
#pragma unroll
            for (int ks = 0; ks < 4; ks++) {
                HU r0, r1;
#pragma unroll
                for (int q = 0; q < 4; q++) {
                    r0.q[q] = __hfma2(c0[ks].q[q], xx0, __hfma2(c1[ks].q[q], gg0, cbh[ks].q[q]));
                    r1.q[q] = __hfma2(c0[ks].q[q], xx1, __hfma2(c1[ks].q[q], gg1, cbh[ks].q[q]));
                }
                if (ks == 0)      { hf0 = r0.v; hf1 = r1.v; }
                else if (ks == 1) { hf2 = r0.v; hf3 = r1.v; }
                else if (ks == 2) { hf4 = r0.v; hf5 = r1.v; }
                else              { hf6 = r0.v; hf7 = r1.v; }
            }
        }
        f32x4 acc[8][2];
#pragma unroll
        for (int af = 0; af < 8; af++) {
            acc[af][0] = (f32x4){0.f, 0.f, 0.f, 0.f};
            acc[af][1] = (f32x4){0.f, 0.f, 0.f, 0.f};
        }
        __builtin_amdgcn_s_setprio(1);
        GEMM_STEP(0, hf0, hf1)
        GEMM_STEP(1, hf2, hf3)
        GEMM_STEP(2, hf4, hf5)
        GEMM_STEP(3, hf6, hf7)
#pragma unroll
        for (int af = 0; af < 8; af++) {             // irfft K-step (+bias at k=0)
            int row = (af << 4) + lr;
            const f16x8 ov = *(const f16x8*)(ldsO + (row << 6) + ((lg ^ (row & 3)) << 4));
            acc[af][0] = MFMA16(ov, tf0, acc[af][0]);
            acc[af][1] = MFMA16(ov, tf1, acc[af][1]);
        }
        __builtin_amdgcn_s_setprio(0);
        if (ti < 3) {                                // prefetch next tile's operands
            int S0n = S0 + 128;
            if (SRC) {
                xv0 = x[(b << 13) + S0n + (wid << 5) + lr];
                xv1 = x[(b << 13) + S0n + (wid << 5) + 16 + lr];
            } else {
                LOAD_HF(S0n)
            }
            LOAD_TF(S0n)
        }
        // current tile's trigD fragments — latency hidden under the gelu epilogue
        f16x8 td0, td1;
        {
            int sgl = S0 + (wid << 5) + (lg << 3);
            td0 = *(const f16x8*)(td_c + (((lr << 13) + sgl) << 1));
            td1 = *(const f16x8*)(td_c + ((((16 + lr) << 13) + sgl) << 1));
        }
#pragma unroll
        for (int bf = 0; bf < 2; bf++) {
            int s_w = (bf << 4) + lr;                // s within this wave's 32
            int s = S0 + (wid << 5) + s_w;
#pragma unroll
            for (int af = 0; af < 8; af++) {
                int o0 = (af << 4) + (lg << 2);
                float v0 = gelu_f(acc[af][bf][0]), v1 = gelu_f(acc[af][bf][1]);
                float v2 = gelu_f(acc[af][bf][2]), v3 = gelu_f(acc[af][bf][3]);
                union { __half2 q[2]; unsigned long long u; } pk;
                pk.q[0] = __floats2half2_rn(v0, v1);
                pk.q[1] = __floats2half2_rn(v2, v3);
                *(unsigned long long*)(hw + (((b << 13) + s) << 8) + (o0 << 1)) = pk.u;
                int byte = (s_w << 8) + ((o0 << 1) ^ ((s_w & 15) << 4));
                *(unsigned long long*)(strip + byte) = pk.u;
            }
        }
        asm volatile("s_waitcnt lgkmcnt(0)" ::: "memory");
        __builtin_amdgcn_sched_barrier(0);
        // per-wave DFT partial over this wave's 32 s (no block barrier)
#pragma unroll
        for (int af = 0; af < 8; af++) {
            int o = (af << 4) + lr;
            union { unsigned int u[4]; f16x8 v; } bb;
#pragma unroll
            for (int p = 0; p < 4; p++) {
                int s0 = (lg << 3) + 2 * p, s1 = s0 + 1;
                unsigned int lo = *(const unsigned short*)
                    (strip + (s0 << 8) + ((o << 1) ^ ((s0 & 15) << 4)));
                unsigned int hi = *(const unsigned short*)
                    (strip + (s1 << 8) + ((o << 1) ^ ((s1 & 15) << 4)));
                bb.u[p] = lo | (hi << 16);
            }
            dacc[af][0] = MFMA16(td0, bb.v, dacc[af][0]);
            dacc[af][1] = MFMA16(td1, bb.v, dacc[af][1]);
        }
    }
    {   // block tree-reduce dacc in the (now dead) stash -> 1 partial per grp
        float* red = (float*)ldsS;
        __syncthreads();
        if (wid == 1 || wid == 3) {
            float* rp = red + ((wid >> 1) << 12) + l6;
#pragma unroll
            for (int af = 0; af < 8; af++)
#pragma unroll
                for (int mh = 0; mh < 2; mh++)
#pragma unroll
                    for (int reg = 0; reg < 4; reg++)
                        rp[((af << 3) + (mh << 2) + reg) << 6] = dacc[af][mh][reg];
        }
        __syncthreads();
        if (wid == 0 || wid == 2) {
            const float* rp = red + ((wid >> 1) << 12) + l6;
#pragma unroll
            for (int af = 0; af < 8; af++)
#pragma unroll
                for (int mh = 0; mh < 2; mh++)
#pragma unroll
                    for (int reg = 0; reg < 4; reg++)
                        dacc[af][mh][reg] += rp[((af << 3) + (mh << 2) + reg) << 6];
        }
        __syncthreads();
        if (wid == 2) {
            float* rp = red + l6;
#pragma unroll
            for (int af = 0; af < 8; af++)
#pragma unroll
                for (int mh = 0; mh < 2; mh++)
#pragma unroll
                    for (int reg = 0; reg < 4; reg++)
                        rp[((af << 3) + (mh << 2) + reg) << 6] = dacc[af][mh][reg];
        }
        __syncthreads();
        if (wid == 0) {
            const float* rp = red + l6;
            float* xp = g_Xfp + (((long)(b << 4) + grp) << 12);
#pragma unroll
            for (int af = 0; af < 8; af++)
#pragma unroll
                for (int mh = 0; mh < 2; mh++)
#pragma unroll
                    for (int reg = 0; reg < 4; reg++) {
                        float v = dacc[af][mh][reg] + rp[((af << 3) + (mh << 2) + reg) << 6];
                        int m2 = (mh << 4) + (lg << 2) + reg;
                        int o = (af << 4) + lr;
                        xp[(m2 << 7) + o] = v;
                    }
        }
    }
}

// ---------------- k_tail: l=3 conv+irfft fused with fc1/gelu/fc2 head ----------------
__global__ __launch_bounds__(256, 2) void k_tail(const __half* __restrict__ h,
                                                 const float* __restrict__ fc1_b,
                                                 const float* __restrict__ fc2_w,
                                                 const float* __restrict__ fc2_b,
                                                 float* __restrict__ out) {
    __shared__ __align__(16) char smem[73728];
    char* ldsA = smem;                               // 32 KB cw(l=3), swizzled
    char* ldsO = smem + 32768;                       // 8 KB om, swizzled
    char* ldsS = smem + 40960;                       // 32 KB stash
    int bi = blockIdx.x;
    int b = bi >> 4, grp = bi & 15;
    int Sg = grp << 9;
    int t = threadIdx.x;
    int wid = __builtin_amdgcn_readfirstlane(t >> 6);
    int l6 = t & 63, lr = l6 & 15, lg = l6 >> 4;
    const char* h_c = (const char*)h;
    const char* cw_c = (const char*)(g_cwh + 3 * CC * CC);
    const char* om_c = (const char*)(g_omh + (b << 12));
    const char* ta_c = (const char*)g_trigA;
    const char* f1_c = (const char*)g_fc1h;
    char* strip = ldsS + (wid << 13);

#pragma unroll
    for (int k = 0; k < 8; k++) {
        int c = (k << 8) + t;
        f16x8 v = *(const f16x8*)(cw_c + (c << 4));
        int row = c >> 4, c16 = c & 15;
        *(f16x8*)(ldsA + (row << 8) + ((c16 ^ (row & 7)) << 4)) = v;
    }
#pragma unroll
    for (int k = 0; k < 2; k++) {
        int c = (k << 8) + t;
        f16x8 v = *(const f16x8*)(om_c + (c << 4));
        int row = c >> 2, c4 = c & 3;
        *(f16x8*)(ldsO + (row << 6) + ((c4 ^ (row & 3)) << 4)) = v;
    }
    f16x8 hf0, hf1, hf2, hf3, hf4, hf5, hf6, hf7, tf0, tf1;
    LOAD_HF(Sg)
    LOAD_TF(Sg)
    __syncthreads();

    float f2b = fc2_b[0];
    for (int ti = 0; ti < 4; ti++) {
        int S0 = Sg + (ti << 7);
        {   // ---- GEMM1: conv1x1 + irfft (no gelu; l=3) -> stash ----
            f32x4 acc[8][2];
#pragma unroll
            for (int af = 0; af < 8; af++) {
                acc[af][0] = (f32x4){0.f, 0.f, 0.f, 0.f};
                acc[af][1] = (f32x4){0.f, 0.f, 0.f, 0.f};
            }
            __builtin_amdgcn_s_setprio(1);
            GEMM_STEP(0, hf0, hf1)
            GEMM_STEP(1, hf2, hf3)
            GEMM_STEP(2, hf4, hf5)
            GEMM_STEP(3, hf6, hf7)
#pragma unroll
            for (int af = 0; af < 8; af++) {
                int row = (af << 4) + lr;
                const f16x8 ov = *(const f16x8*)(ldsO + (row << 6) + ((lg ^ (row & 3)) << 4));
                acc[af][0] = MFMA16(ov, tf0, acc[af][0]);
                acc[af][1] = MFMA16(ov, tf1, acc[af][1]);
            }
            __builtin_amdgcn_s_setprio(0);
            if (ti < 3) {
                int S0n = S0 + 128;
                LOAD_HF(S0n)
                LOAD_TF(S0n)
            }
#pragma unroll
            for (int bf = 0; bf < 2; bf++) {
                int s_w = (bf << 4) + lr;
#pragma unroll
                for (int af = 0; af < 8; af++) {
                    int o0 = (af << 4) + (lg << 2);
                    union { __half2 q[2]; unsigned long long u; } pk;
                    pk.q[0] = __floats2half2_rn(acc[af][bf][0], acc[af][bf][1]);
                    pk.q[1] = __floats2half2_rn(acc[af][bf][2], acc[af][bf][3]);
                    int byte = (s_w << 8) + ((o0 << 1) ^ ((s_w & 15) << 4));
                    *(unsigned long long*)(strip + byte) = pk.u;
                }
            }
        }
        asm volatile("s_waitcnt lgkmcnt(0)" ::: "memory");
        __builtin_amdgcn_sched_barrier(0);
        {   // ---- GEMM2: fc1 (A from L2), B = one swizzled b128 slot per (ks,bf) ----
            f32x4 acc2[8][2];
#pragma unroll
            for (int af = 0; af < 8; af++) {
                acc2[af][0] = (f32x4){0.f, 0.f, 0.f, 0.f};
                acc2[af][1] = (f32x4){0.f, 0.f, 0.f, 0.f};
            }
#pragma unroll
            for (int ks = 0; ks < 4; ks++) {
#pragma unroll
                for (int bf = 0; bf < 2; bf++) {
                    int s_loc = (bf << 4) + lr;
                    int obyte = (((ks << 5) + (lg << 3)) << 1) ^ ((s_loc & 15) << 4);
                    const f16x8 bv = *(const f16x8*)(strip + (s_loc << 8) + obyte);
#pragma unroll
                    for (int af = 0; af < 8; af++) {
                        const f16x8 av = *(const f16x8*)
                            (f1_c + (((af << 4) + lr) << 8) + (ks << 6) + (lg << 4));
                        acc2[af][bf] = MFMA16(av, bv, acc2[af][bf]);
                    }
                }
            }
            float p[2] = {0.f, 0.f};
#pragma unroll
            for (int af = 0; af < 8; af++) {
                float4 fb = *(const float4*)(fc1_b + (af << 4) + (lg << 2));
                float4 f2 = *(const float4*)(fc2_w + (af << 4) + (lg << 2));
#pragma unroll
                for (int bf = 0; bf < 2; bf++) {
                    float v0 = gelu_f(acc2[af][bf][0] + fb.x);
                    float v1 = gelu_f(acc2[af][bf][1] + fb.y);
                    float v2 = gelu_f(acc2[af][bf][2] + fb.z);
                    float v3 = gelu_f(acc2[af][bf][3] + fb.w);
                    p[bf] += f2.x * v0 + f2.y * v1 + f2.z * v2 + f2.w * v3;
                }
            }
#pragma unroll
            for (int bf = 0; bf < 2; bf++) {
                float v = p[bf];
                v += __shfl_xor(v, 16, 64);
                v += __shfl_xor(v, 32, 64);
                if (lg == 0) out[(b << 13) + S0 + (wid << 5) + (bf << 4) + lr] = v + f2b;
            }
        }
    }
}

extern "C" void kernel_launch(void* const* d_in, const int* in_sizes, int n_in,
                              void* d_out, int out_size, void* d_ws, size_t ws_size,
                              hipStream_t stream) {
    const float* x      = (const float*)d_in[0];
    const float* w1_re  = (const float*)d_in[1];
    const float* w1_im  = (const float*)d_in[2];
    const float* gamma  = (const float*)d_in[3];
    const float* fwhm   = (const float*)d_in[4];
    const float* w2     = (const float*)d_in[5];
    const float* cw     = (const float*)d_in[6];
    const float* cb     = (const float*)d_in[7];
    const float* fc0_w  = (const float*)d_in[8];
    const float* fc0_b  = (const float*)d_in[9];
    const float* fc1_w  = (const float*)d_in[10];
    const float* fc1_b  = (const float*)d_in[11];
    const float* fc2_w  = (const float*)d_in[12];
    const float* fc2_b  = (const float*)d_in[13];
    float* out = (float*)d_out;

    __half* h = (__half*)d_ws;                      // 64 MiB, [b][s][i]

    k_prep2<<<dim3(288), dim3(256), 0, stream>>>(cw, fc1_w);
    k_dftx<<<dim3(33), dim3(256), 0, stream>>>(x);
    k_xf0<<<dim3(512), dim3(256), 0, stream>>>(fc0_w, fc0_b);
    for (int l = 0; l < NL; l++) {
        k_mix<<<dim3(256), dim3(256), 0, stream>>>(w1_re, w1_im, gamma, fwhm, w2, cb, l);
        if (l == 0) {
            k_layer<1><<<dim3(512), dim3(256), 0, stream>>>(h, x, fc0_w, fc0_b, l);
            k_red2<<<dim3(512), dim3(256), 0, stream>>>();
        } else if (l < NL - 1) {
            k_layer<0><<<dim3(512), dim3(256), 0, stream>>>(h, x, fc0_w, fc0_b, l);
            k_red2<<<dim3(512), dim3(256), 0, stream>>>();
        } else {
            k_tail<<<dim3(512), dim3(256), 0, stream>>>(h, fc1_b, fc2_w, fc2_b, out);
        }
    }
}